// Round 1
// baseline (4901.478 us; speedup 1.0000x reference)
//
#include <hip/hip_runtime.h>

#define N_JOB 500000
#define N_WORKER 50000
#define E_PRE 4000000
#define E_NXT 4000000
#define E_PROC 2000000

// ---------------------------------------------------------------------------
// Degree counting: int atomics into a 5*N_JOB int region (later converted in
// place to float normalizers: rsqrt(deg) x4, 1/cnt x1).
// ---------------------------------------------------------------------------
__global__ void degrees_kernel(const int* __restrict__ pre_src, const int* __restrict__ pre_dst,
                               const int* __restrict__ nxt_src, const int* __restrict__ nxt_dst,
                               const int* __restrict__ proc_dst, int* __restrict__ deg) {
    int i = blockIdx.x * blockDim.x + threadIdx.x;
    if (i < E_PRE) {
        atomicAdd(&deg[0 * N_JOB + pre_src[i]], 1);
        atomicAdd(&deg[1 * N_JOB + pre_dst[i]], 1);
    }
    if (i < E_NXT) {
        atomicAdd(&deg[2 * N_JOB + nxt_src[i]], 1);
        atomicAdd(&deg[3 * N_JOB + nxt_dst[i]], 1);
    }
    if (i < E_PROC) {
        atomicAdd(&deg[4 * N_JOB + proc_dst[i]], 1);
    }
}

__global__ void convert_kernel(float* __restrict__ base) {
    int i = blockIdx.x * blockDim.x + threadIdx.x;
    if (i >= 5 * N_JOB) return;
    int d = ((const int*)base)[i];
    float fd = (float)(d < 1 ? 1 : d);
    base[i] = (i >= 4 * N_JOB) ? (1.0f / fd) : rsqrtf(fd);
}

// ---------------------------------------------------------------------------
// Embedding: one thread per row, weights staged in LDS.
// ---------------------------------------------------------------------------
template <int F>
__global__ void embed_kernel(const float* __restrict__ feat, const float* __restrict__ W,
                             const float* __restrict__ b, float* __restrict__ out, int n) {
    __shared__ float Ws[F * 16];
    __shared__ float bs[16];
    int t = threadIdx.x;
    if (t < F * 16) Ws[t] = W[t];
    if (t < 16) bs[t] = b[t];
    __syncthreads();
    int i = blockIdx.x * blockDim.x + t;
    if (i >= n) return;
    float f[F];
#pragma unroll
    for (int k = 0; k < F; k++) f[k] = feat[(size_t)i * F + k];
    float o[16];
#pragma unroll
    for (int d = 0; d < 16; d++) {
        float s = bs[d];
#pragma unroll
        for (int k = 0; k < F; k++) s += f[k] * Ws[k * 16 + d];
        o[d] = s;
    }
    float4* dst4 = (float4*)(out + (size_t)i * 16);
    dst4[0] = make_float4(o[0], o[1], o[2], o[3]);
    dst4[1] = make_float4(o[4], o[5], o[6], o[7]);
    dst4[2] = make_float4(o[8], o[9], o[10], o[11]);
    dst4[3] = make_float4(o[12], o[13], o[14], o[15]);
}

// ---------------------------------------------------------------------------
// Edge scatter: 4 threads per edge, each handles one float4 of the message.
// message = h[src] * (scale ? scale[src] : 1); atomicAdd into agg[dst].
// ---------------------------------------------------------------------------
__global__ void scatter_kernel(const float* __restrict__ h, const float* __restrict__ scale,
                               const int* __restrict__ src, const int* __restrict__ dst,
                               float* __restrict__ agg, int E) {
    unsigned gid = blockIdx.x * blockDim.x + threadIdx.x;
    unsigned e = gid >> 2;
    unsigned c = gid & 3;
    if (e >= (unsigned)E) return;
    int s = src[e];
    int d = dst[e];
    float4 v = ((const float4*)(h + (size_t)s * 16))[c];
    float sc = scale ? scale[s] : 1.0f;
    float* ap = agg + (size_t)d * 16 + c * 4;
    atomicAdd(ap + 0, v.x * sc);
    atomicAdd(ap + 1, v.y * sc);
    atomicAdd(ap + 2, v.z * sc);
    atomicAdd(ap + 3, v.w * sc);
}

// ---------------------------------------------------------------------------
// Per-node transforms (16x16 matmul, weights in LDS). Each also zeroes agg
// for the next scatter pass.
// ---------------------------------------------------------------------------
__global__ void xform_first_kernel(float* __restrict__ agg, const float* __restrict__ rs_in,
                                   const float* __restrict__ W,
                                   const float* __restrict__ b0, const float* __restrict__ b1,
                                   const float* __restrict__ b2, float* __restrict__ out) {
    __shared__ float Ws[256];
    __shared__ float bs[16];
    int t = threadIdx.x;
    Ws[t] = W[t];
    if (t < 16) bs[t] = b0[t] + b1[t] + b2[t];
    __syncthreads();
    int v = blockIdx.x * blockDim.x + t;
    if (v >= N_JOB) return;
    float r = rs_in[v];
    float4* ag4 = (float4*)(agg + (size_t)v * 16);
    float a[16];
    {
        float4 A0 = ag4[0], A1 = ag4[1], A2 = ag4[2], A3 = ag4[3];
        a[0] = A0.x * r;  a[1] = A0.y * r;  a[2] = A0.z * r;  a[3] = A0.w * r;
        a[4] = A1.x * r;  a[5] = A1.y * r;  a[6] = A1.z * r;  a[7] = A1.w * r;
        a[8] = A2.x * r;  a[9] = A2.y * r;  a[10] = A2.z * r; a[11] = A2.w * r;
        a[12] = A3.x * r; a[13] = A3.y * r; a[14] = A3.z * r; a[15] = A3.w * r;
    }
    float4 z = make_float4(0.f, 0.f, 0.f, 0.f);
    ag4[0] = z; ag4[1] = z; ag4[2] = z; ag4[3] = z;
    float o[16];
#pragma unroll
    for (int d = 0; d < 16; d++) {
        float s = bs[d];
#pragma unroll
        for (int k = 0; k < 16; k++) s += a[k] * Ws[k * 16 + d];
        o[d] = s;
    }
    float4* dst4 = (float4*)(out + (size_t)v * 16);
    dst4[0] = make_float4(o[0], o[1], o[2], o[3]);
    dst4[1] = make_float4(o[4], o[5], o[6], o[7]);
    dst4[2] = make_float4(o[8], o[9], o[10], o[11]);
    dst4[3] = make_float4(o[12], o[13], o[14], o[15]);
}

__global__ void xform_acc_kernel(float* __restrict__ agg, const float* __restrict__ rs_in,
                                 const float* __restrict__ W, float* __restrict__ out) {
    __shared__ float Ws[256];
    int t = threadIdx.x;
    Ws[t] = W[t];
    __syncthreads();
    int v = blockIdx.x * blockDim.x + t;
    if (v >= N_JOB) return;
    float r = rs_in[v];
    float4* ag4 = (float4*)(agg + (size_t)v * 16);
    float a[16];
    {
        float4 A0 = ag4[0], A1 = ag4[1], A2 = ag4[2], A3 = ag4[3];
        a[0] = A0.x * r;  a[1] = A0.y * r;  a[2] = A0.z * r;  a[3] = A0.w * r;
        a[4] = A1.x * r;  a[5] = A1.y * r;  a[6] = A1.z * r;  a[7] = A1.w * r;
        a[8] = A2.x * r;  a[9] = A2.y * r;  a[10] = A2.z * r; a[11] = A2.w * r;
        a[12] = A3.x * r; a[13] = A3.y * r; a[14] = A3.z * r; a[15] = A3.w * r;
    }
    float4 z = make_float4(0.f, 0.f, 0.f, 0.f);
    ag4[0] = z; ag4[1] = z; ag4[2] = z; ag4[3] = z;
    float4* dst4 = (float4*)(out + (size_t)v * 16);
    float4 O0 = dst4[0], O1 = dst4[1], O2 = dst4[2], O3 = dst4[3];
    float o[16];
    o[0] = O0.x; o[1] = O0.y; o[2] = O0.z; o[3] = O0.w;
    o[4] = O1.x; o[5] = O1.y; o[6] = O1.z; o[7] = O1.w;
    o[8] = O2.x; o[9] = O2.y; o[10] = O2.z; o[11] = O2.w;
    o[12] = O3.x; o[13] = O3.y; o[14] = O3.z; o[15] = O3.w;
#pragma unroll
    for (int d = 0; d < 16; d++) {
        float s = 0.f;
#pragma unroll
        for (int k = 0; k < 16; k++) s += a[k] * Ws[k * 16 + d];
        o[d] += s;
    }
    dst4[0] = make_float4(o[0], o[1], o[2], o[3]);
    dst4[1] = make_float4(o[4], o[5], o[6], o[7]);
    dst4[2] = make_float4(o[8], o[9], o[10], o[11]);
    dst4[3] = make_float4(o[12], o[13], o[14], o[15]);
}

__global__ void xform_sage_kernel(float* __restrict__ agg, const float* __restrict__ inv_cnt,
                                  const float* __restrict__ self_h,
                                  const float* __restrict__ Wself, const float* __restrict__ Wneigh,
                                  float* __restrict__ out) {
    __shared__ float Ws[256];
    __shared__ float Wn[256];
    int t = threadIdx.x;
    Ws[t] = Wself[t];
    Wn[t] = Wneigh[t];
    __syncthreads();
    int v = blockIdx.x * blockDim.x + t;
    if (v >= N_JOB) return;
    float r = inv_cnt[v];
    float4* ag4 = (float4*)(agg + (size_t)v * 16);
    float a[16];
    {
        float4 A0 = ag4[0], A1 = ag4[1], A2 = ag4[2], A3 = ag4[3];
        a[0] = A0.x * r;  a[1] = A0.y * r;  a[2] = A0.z * r;  a[3] = A0.w * r;
        a[4] = A1.x * r;  a[5] = A1.y * r;  a[6] = A1.z * r;  a[7] = A1.w * r;
        a[8] = A2.x * r;  a[9] = A2.y * r;  a[10] = A2.z * r; a[11] = A2.w * r;
        a[12] = A3.x * r; a[13] = A3.y * r; a[14] = A3.z * r; a[15] = A3.w * r;
    }
    float4 z = make_float4(0.f, 0.f, 0.f, 0.f);
    ag4[0] = z; ag4[1] = z; ag4[2] = z; ag4[3] = z;
    float h[16];
    {
        const float4* sh4 = (const float4*)(self_h + (size_t)v * 16);
        float4 H0 = sh4[0], H1 = sh4[1], H2 = sh4[2], H3 = sh4[3];
        h[0] = H0.x; h[1] = H0.y; h[2] = H0.z; h[3] = H0.w;
        h[4] = H1.x; h[5] = H1.y; h[6] = H1.z; h[7] = H1.w;
        h[8] = H2.x; h[9] = H2.y; h[10] = H2.z; h[11] = H2.w;
        h[12] = H3.x; h[13] = H3.y; h[14] = H3.z; h[15] = H3.w;
    }
    float4* dst4 = (float4*)(out + (size_t)v * 16);
    float4 O0 = dst4[0], O1 = dst4[1], O2 = dst4[2], O3 = dst4[3];
    float o[16];
    o[0] = O0.x; o[1] = O0.y; o[2] = O0.z; o[3] = O0.w;
    o[4] = O1.x; o[5] = O1.y; o[6] = O1.z; o[7] = O1.w;
    o[8] = O2.x; o[9] = O2.y; o[10] = O2.z; o[11] = O2.w;
    o[12] = O3.x; o[13] = O3.y; o[14] = O3.z; o[15] = O3.w;
#pragma unroll
    for (int d = 0; d < 16; d++) {
        float s = 0.f;
#pragma unroll
        for (int k = 0; k < 16; k++) s += a[k] * Wn[k * 16 + d] + h[k] * Ws[k * 16 + d];
        o[d] += s;
    }
    dst4[0] = make_float4(o[0], o[1], o[2], o[3]);
    dst4[1] = make_float4(o[4], o[5], o[6], o[7]);
    dst4[2] = make_float4(o[8], o[9], o[10], o[11]);
    dst4[3] = make_float4(o[12], o[13], o[14], o[15]);
}

// ---------------------------------------------------------------------------
// Readout: per-edge dot product.
// ---------------------------------------------------------------------------
__global__ void scores_kernel(const float* __restrict__ hw, const float* __restrict__ hj,
                              const int* __restrict__ src, const int* __restrict__ dst,
                              float* __restrict__ out) {
    int e = blockIdx.x * blockDim.x + threadIdx.x;
    if (e >= E_PROC) return;
    const float4* a = (const float4*)(hw + (size_t)src[e] * 16);
    const float4* b = (const float4*)(hj + (size_t)dst[e] * 16);
    float s = 0.f;
#pragma unroll
    for (int c = 0; c < 4; c++) {
        float4 av = a[c], bv = b[c];
        s += av.x * bv.x + av.y * bv.y + av.z * bv.z + av.w * bv.w;
    }
    out[e] = s;
}

extern "C" void kernel_launch(void* const* d_in, const int* in_sizes, int n_in,
                              void* d_out, int out_size, void* d_ws, size_t ws_size,
                              hipStream_t stream) {
    const float* job_feat     = (const float*)d_in[0];
    const float* worker_feat  = (const float*)d_in[1];
    const int*   pre_src      = (const int*)d_in[2];
    const int*   pre_dst      = (const int*)d_in[3];
    const int*   nxt_src      = (const int*)d_in[4];
    const int*   nxt_dst      = (const int*)d_in[5];
    const int*   proc_src     = (const int*)d_in[6];
    const int*   proc_dst     = (const int*)d_in[7];
    const float* W_emb_job    = (const float*)d_in[8];
    const float* b_emb_job    = (const float*)d_in[9];
    const float* W_emb_worker = (const float*)d_in[10];
    const float* b_emb_worker = (const float*)d_in[11];
    const float* W_pre        = (const float*)d_in[12];
    const float* b_pre        = (const float*)d_in[13];
    const float* W_nxt        = (const float*)d_in[14];
    const float* b_nxt        = (const float*)d_in[15];
    const float* W_self       = (const float*)d_in[16];
    const float* W_neigh      = (const float*)d_in[17];
    const float* b_sage       = (const float*)d_in[18];
    float* out = (float*)d_out;

    float* ws = (float*)d_ws;
    float* hjA = ws;                                  // N_JOB*16
    float* hjB = hjA + (size_t)N_JOB * 16;            // N_JOB*16
    float* hw  = hjB + (size_t)N_JOB * 16;            // N_WORKER*16
    float* agg = hw  + (size_t)N_WORKER * 16;         // N_JOB*16
    float* rs  = agg + (size_t)N_JOB * 16;            // 5*N_JOB (deg ints -> float norms)
    float* rs_out_pre = rs;
    float* rs_in_pre  = rs + 1 * (size_t)N_JOB;
    float* rs_out_nxt = rs + 2 * (size_t)N_JOB;
    float* rs_in_nxt  = rs + 3 * (size_t)N_JOB;
    float* inv_cnt    = rs + 4 * (size_t)N_JOB;

    // Zero agg (16*N_JOB) + degree region (5*N_JOB) in one contiguous memset.
    hipMemsetAsync(agg, 0, (size_t)(16 + 5) * N_JOB * sizeof(float), stream);

    degrees_kernel<<<(E_PRE + 255) / 256, 256, 0, stream>>>(
        pre_src, pre_dst, nxt_src, nxt_dst, proc_dst, (int*)rs);
    convert_kernel<<<(5 * N_JOB + 255) / 256, 256, 0, stream>>>(rs);

    embed_kernel<7><<<(N_JOB + 255) / 256, 256, 0, stream>>>(job_feat, W_emb_job, b_emb_job, hjA, N_JOB);
    embed_kernel<3><<<(N_WORKER + 255) / 256, 256, 0, stream>>>(worker_feat, W_emb_worker, b_emb_worker, hw, N_WORKER);

    float* cur = hjA;
    float* nxt = hjB;
    for (int it = 0; it < 2; it++) {
        scatter_kernel<<<(4 * E_PRE + 255) / 256, 256, 0, stream>>>(cur, rs_out_pre, pre_src, pre_dst, agg, E_PRE);
        xform_first_kernel<<<(N_JOB + 255) / 256, 256, 0, stream>>>(agg, rs_in_pre, W_pre, b_pre, b_nxt, b_sage, nxt);
        scatter_kernel<<<(4 * E_NXT + 255) / 256, 256, 0, stream>>>(cur, rs_out_nxt, nxt_src, nxt_dst, agg, E_NXT);
        xform_acc_kernel<<<(N_JOB + 255) / 256, 256, 0, stream>>>(agg, rs_in_nxt, W_nxt, nxt);
        scatter_kernel<<<(4 * E_PROC + 255) / 256, 256, 0, stream>>>(hw, nullptr, proc_src, proc_dst, agg, E_PROC);
        xform_sage_kernel<<<(N_JOB + 255) / 256, 256, 0, stream>>>(agg, inv_cnt, cur, W_self, W_neigh, nxt);
        float* tmp = cur; cur = nxt; nxt = tmp;
    }

    scores_kernel<<<(E_PROC + 255) / 256, 256, 0, stream>>>(hw, cur, proc_src, proc_dst, out);
}

// Round 2
// 2180.012 us; speedup vs baseline: 2.2484x; 2.2484x over previous
//
#include <hip/hip_runtime.h>

#define N_JOB 500000
#define N_WORKER 50000
#define E_PRE 4000000
#define E_NXT 4000000
#define E_PROC 2000000

#define SCAN_N (3 * N_JOB)         // concatenated in-degrees: [in_pre | in_nxt | in_proc]
#define SCAN_BLK 2048              // 256 threads * 8 elems
#define SCAN_NB ((SCAN_N + SCAN_BLK - 1) / SCAN_BLK)   // 733 (must be <= 1024)

// ---------------------------------------------------------------------------
// Degree counting into 5*N_JOB ints:
//   [0]=in_pre  [1]=in_nxt  [2]=in_proc  [3]=out_pre  [4]=out_nxt
// First 3 segments are also the scan input for CSR row offsets.
// ---------------------------------------------------------------------------
__global__ void degrees_kernel(const int* __restrict__ pre_src, const int* __restrict__ pre_dst,
                               const int* __restrict__ nxt_src, const int* __restrict__ nxt_dst,
                               const int* __restrict__ proc_dst, int* __restrict__ deg) {
    int i = blockIdx.x * blockDim.x + threadIdx.x;
    if (i < E_PRE) {
        atomicAdd(&deg[0 * N_JOB + pre_dst[i]], 1);
        atomicAdd(&deg[3 * N_JOB + pre_src[i]], 1);
    }
    if (i < E_NXT) {
        atomicAdd(&deg[1 * N_JOB + nxt_dst[i]], 1);
        atomicAdd(&deg[4 * N_JOB + nxt_src[i]], 1);
    }
    if (i < E_PROC) {
        atomicAdd(&deg[2 * N_JOB + proc_dst[i]], 1);
    }
}

// Convert degree ints -> normalizer floats in place.
// Segments 0,1,3,4 -> rsqrt(max(d,1)); segment 2 (proc in-count) -> 1/max(d,1).
__global__ void convert_kernel(float* __restrict__ base) {
    int i = blockIdx.x * blockDim.x + threadIdx.x;
    if (i >= 5 * N_JOB) return;
    int d = ((const int*)base)[i];
    float fd = (float)(d < 1 ? 1 : d);
    bool is_cnt = (i >= 2 * N_JOB) && (i < 3 * N_JOB);
    base[i] = is_cnt ? (1.0f / fd) : rsqrtf(fd);
}

// ---------------------------------------------------------------------------
// Exclusive scan over SCAN_N ints (3-kernel two-level scan).
// ---------------------------------------------------------------------------
__global__ void scan_blocksum(const int* __restrict__ in, int* __restrict__ bsum, int n) {
    __shared__ int sd[256];
    int t = threadIdx.x;
    int base = blockIdx.x * SCAN_BLK + t * 8;
    int sum = 0;
#pragma unroll
    for (int j = 0; j < 8; ++j) {
        int idx = base + j;
        if (idx < n) sum += in[idx];
    }
    sd[t] = sum;
    __syncthreads();
    for (int o = 128; o > 0; o >>= 1) {
        if (t < o) sd[t] += sd[t + o];
        __syncthreads();
    }
    if (t == 0) bsum[blockIdx.x] = sd[0];
}

__global__ void scan_bsum(int* __restrict__ bsum, int nb) {
    __shared__ int s[1024];
    int t = threadIdx.x;
    int orig = (t < nb) ? bsum[t] : 0;
    s[t] = orig;
    __syncthreads();
    for (int o = 1; o < 1024; o <<= 1) {
        int v = (t >= o) ? s[t - o] : 0;
        __syncthreads();
        s[t] += v;
        __syncthreads();
    }
    if (t < nb) bsum[t] = s[t] - orig;  // exclusive
}

__global__ void scan_final(const int* __restrict__ in, const int* __restrict__ bsum,
                           int* __restrict__ off, int n) {
    __shared__ int sd[256];
    int t = threadIdx.x;
    int base = blockIdx.x * SCAN_BLK + t * 8;
    int vals[8];
    int tsum = 0;
#pragma unroll
    for (int j = 0; j < 8; ++j) {
        int idx = base + j;
        vals[j] = (idx < n) ? in[idx] : 0;
        tsum += vals[j];
    }
    sd[t] = tsum;
    __syncthreads();
    for (int o = 1; o < 256; o <<= 1) {
        int v = (t >= o) ? sd[t - o] : 0;
        __syncthreads();
        sd[t] += v;
        __syncthreads();
    }
    int run = bsum[blockIdx.x] + sd[t] - tsum;  // block base + exclusive thread prefix
#pragma unroll
    for (int j = 0; j < 8; ++j) {
        int idx = base + j;
        if (idx < n) off[idx] = run;
        run += vals[j];
    }
}

// ---------------------------------------------------------------------------
// CSR placement: off holds exclusive row starts (global edge ids: pre [0,4M),
// nxt [4M,8M), proc [8M,10M)). atomicAdd turns off into row ENDS; adj gets src.
// ---------------------------------------------------------------------------
__global__ void placement_kernel(const int* __restrict__ pre_src, const int* __restrict__ pre_dst,
                                 const int* __restrict__ nxt_src, const int* __restrict__ nxt_dst,
                                 const int* __restrict__ proc_src, const int* __restrict__ proc_dst,
                                 int* __restrict__ off, int* __restrict__ adj) {
    int i = blockIdx.x * blockDim.x + threadIdx.x;
    if (i < E_PRE) {
        int p = atomicAdd(&off[0 * N_JOB + pre_dst[i]], 1);
        adj[p] = pre_src[i];
    }
    if (i < E_NXT) {
        int p = atomicAdd(&off[1 * N_JOB + nxt_dst[i]], 1);
        adj[p] = nxt_src[i];
    }
    if (i < E_PROC) {
        int p = atomicAdd(&off[2 * N_JOB + proc_dst[i]], 1);
        adj[p] = proc_src[i];
    }
}

// ---------------------------------------------------------------------------
// Embedding: one thread per row, weights staged in LDS.
// ---------------------------------------------------------------------------
template <int F>
__global__ void embed_kernel(const float* __restrict__ feat, const float* __restrict__ W,
                             const float* __restrict__ b, float* __restrict__ out, int n) {
    __shared__ float Ws[F * 16];
    __shared__ float bs[16];
    int t = threadIdx.x;
    if (t < F * 16) Ws[t] = W[t];
    if (t < 16) bs[t] = b[t];
    __syncthreads();
    int i = blockIdx.x * blockDim.x + t;
    if (i >= n) return;
    float f[F];
#pragma unroll
    for (int k = 0; k < F; k++) f[k] = feat[(size_t)i * F + k];
    float o[16];
#pragma unroll
    for (int d = 0; d < 16; d++) {
        float s = bs[d];
#pragma unroll
        for (int k = 0; k < F; k++) s += f[k] * Ws[k * 16 + d];
        o[d] = s;
    }
    float4* dst4 = (float4*)(out + (size_t)i * 16);
    dst4[0] = make_float4(o[0], o[1], o[2], o[3]);
    dst4[1] = make_float4(o[4], o[5], o[6], o[7]);
    dst4[2] = make_float4(o[8], o[9], o[10], o[11]);
    dst4[3] = make_float4(o[12], o[13], o[14], o[15]);
}

// ---------------------------------------------------------------------------
// Fused gather + normalize + 16x16 transform. 4 lanes per node; lane c owns
// float4 chunk c. Cross-chunk exchange for the matmul via __shfl(width=4).
// rend points at the row-END array for this graph segment; row start of node v
// is rend[v-1] (or seg_base for v==0).
// ---------------------------------------------------------------------------
__device__ __forceinline__ void mm_accum(const float* __restrict__ Ws, float4 a, int c, float o[4]) {
#pragma unroll
    for (int g = 0; g < 4; ++g) {
        float a0 = __shfl(a.x, g, 4);
        float a1 = __shfl(a.y, g, 4);
        float a2 = __shfl(a.z, g, 4);
        float a3 = __shfl(a.w, g, 4);
        const float* wr = &Ws[(4 * g) * 16 + c * 4];
#pragma unroll
        for (int j = 0; j < 4; ++j)
            o[j] += a0 * wr[j] + a1 * wr[16 + j] + a2 * wr[32 + j] + a3 * wr[48 + j];
    }
}

__global__ void gather_gc_first(const float* __restrict__ h, const float* __restrict__ sc_out,
                                const float* __restrict__ sc_in,
                                const int* __restrict__ adj, const int* __restrict__ rend,
                                int seg_base, const float* __restrict__ W,
                                const float* __restrict__ b0, const float* __restrict__ b1,
                                const float* __restrict__ b2, float* __restrict__ out) {
    __shared__ float Ws[256];
    __shared__ float bs[16];
    int t = threadIdx.x;
    Ws[t] = W[t];
    if (t < 16) bs[t] = b0[t] + b1[t] + b2[t];
    __syncthreads();
    unsigned gid = blockIdx.x * 256 + t;
    unsigned v = gid >> 2, c = gid & 3;
    if (v >= N_JOB) return;
    int end = rend[v];
    int start = (v == 0) ? seg_base : rend[v - 1];
    float4 acc = make_float4(0.f, 0.f, 0.f, 0.f);
    for (int p = start; p < end; ++p) {
        int s = adj[p];
        float4 hv = ((const float4*)(h + (size_t)s * 16))[c];
        float scv = sc_out[s];
        acc.x += hv.x * scv; acc.y += hv.y * scv; acc.z += hv.z * scv; acc.w += hv.w * scv;
    }
    float r = sc_in[v];
    acc.x *= r; acc.y *= r; acc.z *= r; acc.w *= r;
    float o[4];
#pragma unroll
    for (int j = 0; j < 4; ++j) o[j] = bs[c * 4 + j];
    mm_accum(Ws, acc, c, o);
    ((float4*)(out + (size_t)v * 16))[c] = make_float4(o[0], o[1], o[2], o[3]);
}

__global__ void gather_gc_acc(const float* __restrict__ h, const float* __restrict__ sc_out,
                              const float* __restrict__ sc_in,
                              const int* __restrict__ adj, const int* __restrict__ rend,
                              int seg_base, const float* __restrict__ W,
                              float* __restrict__ out) {
    __shared__ float Ws[256];
    int t = threadIdx.x;
    Ws[t] = W[t];
    __syncthreads();
    unsigned gid = blockIdx.x * 256 + t;
    unsigned v = gid >> 2, c = gid & 3;
    if (v >= N_JOB) return;
    int end = rend[v];
    int start = (v == 0) ? seg_base : rend[v - 1];
    float4 acc = make_float4(0.f, 0.f, 0.f, 0.f);
    for (int p = start; p < end; ++p) {
        int s = adj[p];
        float4 hv = ((const float4*)(h + (size_t)s * 16))[c];
        float scv = sc_out[s];
        acc.x += hv.x * scv; acc.y += hv.y * scv; acc.z += hv.z * scv; acc.w += hv.w * scv;
    }
    float r = sc_in[v];
    acc.x *= r; acc.y *= r; acc.z *= r; acc.w *= r;
    float4* op = (float4*)(out + (size_t)v * 16) + c;
    float4 ov = *op;
    float o[4] = {ov.x, ov.y, ov.z, ov.w};
    mm_accum(Ws, acc, c, o);
    *op = make_float4(o[0], o[1], o[2], o[3]);
}

__global__ void gather_sage(const float* __restrict__ hwk, const float* __restrict__ inv_cnt,
                            const int* __restrict__ adj, const int* __restrict__ rend,
                            int seg_base, const float* __restrict__ Wn,
                            const float* __restrict__ Wsf, const float* __restrict__ self_h,
                            float* __restrict__ out) {
    __shared__ float WnS[256];
    __shared__ float WsS[256];
    int t = threadIdx.x;
    WnS[t] = Wn[t];
    WsS[t] = Wsf[t];
    __syncthreads();
    unsigned gid = blockIdx.x * 256 + t;
    unsigned v = gid >> 2, c = gid & 3;
    if (v >= N_JOB) return;
    int end = rend[v];
    int start = (v == 0) ? seg_base : rend[v - 1];
    float4 acc = make_float4(0.f, 0.f, 0.f, 0.f);
    for (int p = start; p < end; ++p) {
        int s = adj[p];
        float4 hv = ((const float4*)(hwk + (size_t)s * 16))[c];
        acc.x += hv.x; acc.y += hv.y; acc.z += hv.z; acc.w += hv.w;
    }
    float r = inv_cnt[v];
    acc.x *= r; acc.y *= r; acc.z *= r; acc.w *= r;
    float4 hs = ((const float4*)(self_h + (size_t)v * 16))[c];
    float4* op = (float4*)(out + (size_t)v * 16) + c;
    float4 ov = *op;
    float o[4] = {ov.x, ov.y, ov.z, ov.w};
    mm_accum(WnS, acc, c, o);
    mm_accum(WsS, hs, c, o);
    *op = make_float4(o[0], o[1], o[2], o[3]);
}

// ---------------------------------------------------------------------------
// Readout: per-edge dot product.
// ---------------------------------------------------------------------------
__global__ void scores_kernel(const float* __restrict__ hwk, const float* __restrict__ hj,
                              const int* __restrict__ src, const int* __restrict__ dst,
                              float* __restrict__ out) {
    int e = blockIdx.x * blockDim.x + threadIdx.x;
    if (e >= E_PROC) return;
    const float4* a = (const float4*)(hwk + (size_t)src[e] * 16);
    const float4* b = (const float4*)(hj + (size_t)dst[e] * 16);
    float s = 0.f;
#pragma unroll
    for (int c = 0; c < 4; c++) {
        float4 av = a[c], bv = b[c];
        s += av.x * bv.x + av.y * bv.y + av.z * bv.z + av.w * bv.w;
    }
    out[e] = s;
}

extern "C" void kernel_launch(void* const* d_in, const int* in_sizes, int n_in,
                              void* d_out, int out_size, void* d_ws, size_t ws_size,
                              hipStream_t stream) {
    const float* job_feat     = (const float*)d_in[0];
    const float* worker_feat  = (const float*)d_in[1];
    const int*   pre_src      = (const int*)d_in[2];
    const int*   pre_dst      = (const int*)d_in[3];
    const int*   nxt_src      = (const int*)d_in[4];
    const int*   nxt_dst      = (const int*)d_in[5];
    const int*   proc_src     = (const int*)d_in[6];
    const int*   proc_dst     = (const int*)d_in[7];
    const float* W_emb_job    = (const float*)d_in[8];
    const float* b_emb_job    = (const float*)d_in[9];
    const float* W_emb_worker = (const float*)d_in[10];
    const float* b_emb_worker = (const float*)d_in[11];
    const float* W_pre        = (const float*)d_in[12];
    const float* b_pre        = (const float*)d_in[13];
    const float* W_nxt        = (const float*)d_in[14];
    const float* b_nxt        = (const float*)d_in[15];
    const float* W_self       = (const float*)d_in[16];
    const float* W_neigh      = (const float*)d_in[17];
    const float* b_sage       = (const float*)d_in[18];
    float* out = (float*)d_out;

    // Workspace layout (floats): ~123 MB total
    float* ws  = (float*)d_ws;
    float* hjA = ws;                                   // 8,000,000
    float* hjB = hjA + (size_t)N_JOB * 16;             // 8,000,000
    float* hw  = hjB + (size_t)N_JOB * 16;             // 800,000
    float* rs  = hw + (size_t)N_WORKER * 16;           // 2,500,000 (deg ints -> norm floats)
    int*   off = (int*)(rs + (size_t)5 * N_JOB);       // 1,500,000 (row offsets -> ends)
    int*   bsum = off + SCAN_N;                        // 1024
    int*   adj = bsum + 1024;                          // 10,000,000

    float* rs_in_pre  = rs + 0 * (size_t)N_JOB;
    float* rs_in_nxt  = rs + 1 * (size_t)N_JOB;
    float* inv_cnt    = rs + 2 * (size_t)N_JOB;
    float* rs_out_pre = rs + 3 * (size_t)N_JOB;
    float* rs_out_nxt = rs + 4 * (size_t)N_JOB;

    // Zero the degree region only.
    hipMemsetAsync(rs, 0, (size_t)5 * N_JOB * sizeof(float), stream);

    degrees_kernel<<<(E_PRE + 255) / 256, 256, 0, stream>>>(
        pre_src, pre_dst, nxt_src, nxt_dst, proc_dst, (int*)rs);

    // CSR row offsets from concatenated in-degrees.
    scan_blocksum<<<SCAN_NB, 256, 0, stream>>>((const int*)rs, bsum, SCAN_N);
    scan_bsum<<<1, 1024, 0, stream>>>(bsum, SCAN_NB);
    scan_final<<<SCAN_NB, 256, 0, stream>>>((const int*)rs, bsum, off, SCAN_N);

    placement_kernel<<<(E_PRE + 255) / 256, 256, 0, stream>>>(
        pre_src, pre_dst, nxt_src, nxt_dst, proc_src, proc_dst, off, adj);

    convert_kernel<<<(5 * N_JOB + 255) / 256, 256, 0, stream>>>(rs);

    embed_kernel<7><<<(N_JOB + 255) / 256, 256, 0, stream>>>(job_feat, W_emb_job, b_emb_job, hjA, N_JOB);
    embed_kernel<3><<<(N_WORKER + 255) / 256, 256, 0, stream>>>(worker_feat, W_emb_worker, b_emb_worker, hw, N_WORKER);

    const int GGRID = (4 * N_JOB + 255) / 256;
    float* cur = hjA;
    float* nx  = hjB;
    for (int it = 0; it < 2; it++) {
        gather_gc_first<<<GGRID, 256, 0, stream>>>(cur, rs_out_pre, rs_in_pre, adj,
                                                   off + 0 * N_JOB, 0, W_pre,
                                                   b_pre, b_nxt, b_sage, nx);
        gather_gc_acc<<<GGRID, 256, 0, stream>>>(cur, rs_out_nxt, rs_in_nxt, adj,
                                                 off + 1 * N_JOB, E_PRE, W_nxt, nx);
        gather_sage<<<GGRID, 256, 0, stream>>>(hw, inv_cnt, adj, off + 2 * N_JOB,
                                               E_PRE + E_NXT, W_neigh, W_self, cur, nx);
        float* tmp = cur; cur = nx; nx = tmp;
    }

    scores_kernel<<<(E_PROC + 255) / 256, 256, 0, stream>>>(hw, cur, proc_src, proc_dst, out);
}

// Round 3
// 1824.741 us; speedup vs baseline: 2.6861x; 1.1947x over previous
//
#include <hip/hip_runtime.h>

#define N_JOB 500000
#define N_WORKER 50000
#define E_PRE 4000000
#define E_NXT 4000000
#define E_PROC 2000000

#define SCAN_N (3 * N_JOB)         // concatenated in-degrees: [in_pre | in_nxt | in_proc]
#define SCAN_BLK 2048              // 256 threads * 8 elems
#define SCAN_NB ((SCAN_N + SCAN_BLK - 1) / SCAN_BLK)   // 733 (must be <= 1024)

#define KWIN 8
#define WIN_SZ ((N_JOB + KWIN - 1) / KWIN)             // 62500

// ---------------------------------------------------------------------------
// Windowed degree counting into 5*N_JOB ints:
//   [0]=in_pre  [1]=in_nxt  [2]=in_proc  [3]=out_pre  [4]=out_nxt
// Pass w only touches counters for node ids in [wlo,whi) -> atomics stay in a
// ~1.2MB L2-hot slice instead of random RMW over 10MB.
// ---------------------------------------------------------------------------
__global__ void degrees_win_kernel(const int* __restrict__ pre_src, const int* __restrict__ pre_dst,
                                   const int* __restrict__ nxt_src, const int* __restrict__ nxt_dst,
                                   const int* __restrict__ proc_dst, int* __restrict__ deg,
                                   int wlo, int whi) {
    int i = blockIdx.x * blockDim.x + threadIdx.x;
    if (i < E_PRE) {
        int d = pre_dst[i];
        if (d >= wlo && d < whi) atomicAdd(&deg[0 * N_JOB + d], 1);
        int s = pre_src[i];
        if (s >= wlo && s < whi) atomicAdd(&deg[3 * N_JOB + s], 1);
    }
    if (i < E_NXT) {
        int d = nxt_dst[i];
        if (d >= wlo && d < whi) atomicAdd(&deg[1 * N_JOB + d], 1);
        int s = nxt_src[i];
        if (s >= wlo && s < whi) atomicAdd(&deg[4 * N_JOB + s], 1);
    }
    if (i < E_PROC) {
        int d = proc_dst[i];
        if (d >= wlo && d < whi) atomicAdd(&deg[2 * N_JOB + d], 1);
    }
}

// Convert degree ints -> normalizer floats in place.
// Segments 0,1,3,4 -> rsqrt(max(d,1)); segment 2 (proc in-count) -> 1/max(d,1).
__global__ void convert_kernel(float* __restrict__ base) {
    int i = blockIdx.x * blockDim.x + threadIdx.x;
    if (i >= 5 * N_JOB) return;
    int d = ((const int*)base)[i];
    float fd = (float)(d < 1 ? 1 : d);
    bool is_cnt = (i >= 2 * N_JOB) && (i < 3 * N_JOB);
    base[i] = is_cnt ? (1.0f / fd) : rsqrtf(fd);
}

// ---------------------------------------------------------------------------
// Exclusive scan over SCAN_N ints (3-kernel two-level scan).
// ---------------------------------------------------------------------------
__global__ void scan_blocksum(const int* __restrict__ in, int* __restrict__ bsum, int n) {
    __shared__ int sd[256];
    int t = threadIdx.x;
    int base = blockIdx.x * SCAN_BLK + t * 8;
    int sum = 0;
#pragma unroll
    for (int j = 0; j < 8; ++j) {
        int idx = base + j;
        if (idx < n) sum += in[idx];
    }
    sd[t] = sum;
    __syncthreads();
    for (int o = 128; o > 0; o >>= 1) {
        if (t < o) sd[t] += sd[t + o];
        __syncthreads();
    }
    if (t == 0) bsum[blockIdx.x] = sd[0];
}

__global__ void scan_bsum(int* __restrict__ bsum, int nb) {
    __shared__ int s[1024];
    int t = threadIdx.x;
    int orig = (t < nb) ? bsum[t] : 0;
    s[t] = orig;
    __syncthreads();
    for (int o = 1; o < 1024; o <<= 1) {
        int v = (t >= o) ? s[t - o] : 0;
        __syncthreads();
        s[t] += v;
        __syncthreads();
    }
    if (t < nb) bsum[t] = s[t] - orig;  // exclusive
}

__global__ void scan_final(const int* __restrict__ in, const int* __restrict__ bsum,
                           int* __restrict__ off, int n) {
    __shared__ int sd[256];
    int t = threadIdx.x;
    int base = blockIdx.x * SCAN_BLK + t * 8;
    int vals[8];
    int tsum = 0;
#pragma unroll
    for (int j = 0; j < 8; ++j) {
        int idx = base + j;
        vals[j] = (idx < n) ? in[idx] : 0;
        tsum += vals[j];
    }
    sd[t] = tsum;
    __syncthreads();
    for (int o = 1; o < 256; o <<= 1) {
        int v = (t >= o) ? sd[t - o] : 0;
        __syncthreads();
        sd[t] += v;
        __syncthreads();
    }
    int run = bsum[blockIdx.x] + sd[t] - tsum;  // block base + exclusive thread prefix
#pragma unroll
    for (int j = 0; j < 8; ++j) {
        int idx = base + j;
        if (idx < n) off[idx] = run;
        run += vals[j];
    }
}

// ---------------------------------------------------------------------------
// Windowed CSR placement: pass w only places edges with dst in [wlo,whi), so
// the off-atomics slice (~250KB) and adj write region (~5MB) stay L2-hot and
// scattered 4B writes merge in cache before writeback.
// Global edge ids: pre [0,4M), nxt [4M,8M), proc [8M,10M).
// ---------------------------------------------------------------------------
__global__ void placement_win_kernel(const int* __restrict__ pre_src, const int* __restrict__ pre_dst,
                                     const int* __restrict__ nxt_src, const int* __restrict__ nxt_dst,
                                     const int* __restrict__ proc_src, const int* __restrict__ proc_dst,
                                     int* __restrict__ off, int* __restrict__ adj,
                                     int wlo, int whi) {
    int i = blockIdx.x * blockDim.x + threadIdx.x;
    if (i < E_PRE) {
        int d = pre_dst[i];
        if (d >= wlo && d < whi) {
            int p = atomicAdd(&off[0 * N_JOB + d], 1);
            adj[p] = pre_src[i];
        }
    }
    if (i < E_NXT) {
        int d = nxt_dst[i];
        if (d >= wlo && d < whi) {
            int p = atomicAdd(&off[1 * N_JOB + d], 1);
            adj[p] = nxt_src[i];
        }
    }
    if (i < E_PROC) {
        int d = proc_dst[i];
        if (d >= wlo && d < whi) {
            int p = atomicAdd(&off[2 * N_JOB + d], 1);
            adj[p] = proc_src[i];
        }
    }
}

// ---------------------------------------------------------------------------
// Embedding: one thread per row, weights staged in LDS.
// ---------------------------------------------------------------------------
template <int F>
__global__ void embed_kernel(const float* __restrict__ feat, const float* __restrict__ W,
                             const float* __restrict__ b, float* __restrict__ out, int n) {
    __shared__ float Ws[F * 16];
    __shared__ float bs[16];
    int t = threadIdx.x;
    if (t < F * 16) Ws[t] = W[t];
    if (t < 16) bs[t] = b[t];
    __syncthreads();
    int i = blockIdx.x * blockDim.x + t;
    if (i >= n) return;
    float f[F];
#pragma unroll
    for (int k = 0; k < F; k++) f[k] = feat[(size_t)i * F + k];
    float o[16];
#pragma unroll
    for (int d = 0; d < 16; d++) {
        float s = bs[d];
#pragma unroll
        for (int k = 0; k < F; k++) s += f[k] * Ws[k * 16 + d];
        o[d] = s;
    }
    float4* dst4 = (float4*)(out + (size_t)i * 16);
    dst4[0] = make_float4(o[0], o[1], o[2], o[3]);
    dst4[1] = make_float4(o[4], o[5], o[6], o[7]);
    dst4[2] = make_float4(o[8], o[9], o[10], o[11]);
    dst4[3] = make_float4(o[12], o[13], o[14], o[15]);
}

// ---------------------------------------------------------------------------
// Fused gather + normalize + 16x16 transform. 4 lanes per node; lane c owns
// float4 chunk c. Cross-chunk exchange for the matmul via __shfl(width=4).
// rend points at the row-END array for this graph segment; row start of node v
// is rend[v-1] (or seg_base for v==0).
// ---------------------------------------------------------------------------
__device__ __forceinline__ void mm_accum(const float* __restrict__ Ws, float4 a, int c, float o[4]) {
#pragma unroll
    for (int g = 0; g < 4; ++g) {
        float a0 = __shfl(a.x, g, 4);
        float a1 = __shfl(a.y, g, 4);
        float a2 = __shfl(a.z, g, 4);
        float a3 = __shfl(a.w, g, 4);
        const float* wr = &Ws[(4 * g) * 16 + c * 4];
#pragma unroll
        for (int j = 0; j < 4; ++j)
            o[j] += a0 * wr[j] + a1 * wr[16 + j] + a2 * wr[32 + j] + a3 * wr[48 + j];
    }
}

__global__ void gather_gc_first(const float* __restrict__ h, const float* __restrict__ sc_out,
                                const float* __restrict__ sc_in,
                                const int* __restrict__ adj, const int* __restrict__ rend,
                                int seg_base, const float* __restrict__ W,
                                const float* __restrict__ b0, const float* __restrict__ b1,
                                const float* __restrict__ b2, float* __restrict__ out) {
    __shared__ float Ws[256];
    __shared__ float bs[16];
    int t = threadIdx.x;
    Ws[t] = W[t];
    if (t < 16) bs[t] = b0[t] + b1[t] + b2[t];
    __syncthreads();
    unsigned gid = blockIdx.x * 256 + t;
    unsigned v = gid >> 2, c = gid & 3;
    if (v >= N_JOB) return;
    int end = rend[v];
    int start = (v == 0) ? seg_base : rend[v - 1];
    float4 acc = make_float4(0.f, 0.f, 0.f, 0.f);
    for (int p = start; p < end; ++p) {
        int s = adj[p];
        float4 hv = ((const float4*)(h + (size_t)s * 16))[c];
        float scv = sc_out[s];
        acc.x += hv.x * scv; acc.y += hv.y * scv; acc.z += hv.z * scv; acc.w += hv.w * scv;
    }
    float r = sc_in[v];
    acc.x *= r; acc.y *= r; acc.z *= r; acc.w *= r;
    float o[4];
#pragma unroll
    for (int j = 0; j < 4; ++j) o[j] = bs[c * 4 + j];
    mm_accum(Ws, acc, c, o);
    ((float4*)(out + (size_t)v * 16))[c] = make_float4(o[0], o[1], o[2], o[3]);
}

__global__ void gather_gc_acc(const float* __restrict__ h, const float* __restrict__ sc_out,
                              const float* __restrict__ sc_in,
                              const int* __restrict__ adj, const int* __restrict__ rend,
                              int seg_base, const float* __restrict__ W,
                              float* __restrict__ out) {
    __shared__ float Ws[256];
    int t = threadIdx.x;
    Ws[t] = W[t];
    __syncthreads();
    unsigned gid = blockIdx.x * 256 + t;
    unsigned v = gid >> 2, c = gid & 3;
    if (v >= N_JOB) return;
    int end = rend[v];
    int start = (v == 0) ? seg_base : rend[v - 1];
    float4 acc = make_float4(0.f, 0.f, 0.f, 0.f);
    for (int p = start; p < end; ++p) {
        int s = adj[p];
        float4 hv = ((const float4*)(h + (size_t)s * 16))[c];
        float scv = sc_out[s];
        acc.x += hv.x * scv; acc.y += hv.y * scv; acc.z += hv.z * scv; acc.w += hv.w * scv;
    }
    float r = sc_in[v];
    acc.x *= r; acc.y *= r; acc.z *= r; acc.w *= r;
    float4* op = (float4*)(out + (size_t)v * 16) + c;
    float4 ov = *op;
    float o[4] = {ov.x, ov.y, ov.z, ov.w};
    mm_accum(Ws, acc, c, o);
    *op = make_float4(o[0], o[1], o[2], o[3]);
}

__global__ void gather_sage(const float* __restrict__ hwk, const float* __restrict__ inv_cnt,
                            const int* __restrict__ adj, const int* __restrict__ rend,
                            int seg_base, const float* __restrict__ Wn,
                            const float* __restrict__ Wsf, const float* __restrict__ self_h,
                            float* __restrict__ out) {
    __shared__ float WnS[256];
    __shared__ float WsS[256];
    int t = threadIdx.x;
    WnS[t] = Wn[t];
    WsS[t] = Wsf[t];
    __syncthreads();
    unsigned gid = blockIdx.x * 256 + t;
    unsigned v = gid >> 2, c = gid & 3;
    if (v >= N_JOB) return;
    int end = rend[v];
    int start = (v == 0) ? seg_base : rend[v - 1];
    float4 acc = make_float4(0.f, 0.f, 0.f, 0.f);
    for (int p = start; p < end; ++p) {
        int s = adj[p];
        float4 hv = ((const float4*)(hwk + (size_t)s * 16))[c];
        acc.x += hv.x; acc.y += hv.y; acc.z += hv.z; acc.w += hv.w;
    }
    float r = inv_cnt[v];
    acc.x *= r; acc.y *= r; acc.z *= r; acc.w *= r;
    float4 hs = ((const float4*)(self_h + (size_t)v * 16))[c];
    float4* op = (float4*)(out + (size_t)v * 16) + c;
    float4 ov = *op;
    float o[4] = {ov.x, ov.y, ov.z, ov.w};
    mm_accum(WnS, acc, c, o);
    mm_accum(WsS, hs, c, o);
    *op = make_float4(o[0], o[1], o[2], o[3]);
}

// ---------------------------------------------------------------------------
// Readout: per-edge dot product.
// ---------------------------------------------------------------------------
__global__ void scores_kernel(const float* __restrict__ hwk, const float* __restrict__ hj,
                              const int* __restrict__ src, const int* __restrict__ dst,
                              float* __restrict__ out) {
    int e = blockIdx.x * blockDim.x + threadIdx.x;
    if (e >= E_PROC) return;
    const float4* a = (const float4*)(hwk + (size_t)src[e] * 16);
    const float4* b = (const float4*)(hj + (size_t)dst[e] * 16);
    float s = 0.f;
#pragma unroll
    for (int c = 0; c < 4; c++) {
        float4 av = a[c], bv = b[c];
        s += av.x * bv.x + av.y * bv.y + av.z * bv.z + av.w * bv.w;
    }
    out[e] = s;
}

extern "C" void kernel_launch(void* const* d_in, const int* in_sizes, int n_in,
                              void* d_out, int out_size, void* d_ws, size_t ws_size,
                              hipStream_t stream) {
    const float* job_feat     = (const float*)d_in[0];
    const float* worker_feat  = (const float*)d_in[1];
    const int*   pre_src      = (const int*)d_in[2];
    const int*   pre_dst      = (const int*)d_in[3];
    const int*   nxt_src      = (const int*)d_in[4];
    const int*   nxt_dst      = (const int*)d_in[5];
    const int*   proc_src     = (const int*)d_in[6];
    const int*   proc_dst     = (const int*)d_in[7];
    const float* W_emb_job    = (const float*)d_in[8];
    const float* b_emb_job    = (const float*)d_in[9];
    const float* W_emb_worker = (const float*)d_in[10];
    const float* b_emb_worker = (const float*)d_in[11];
    const float* W_pre        = (const float*)d_in[12];
    const float* b_pre        = (const float*)d_in[13];
    const float* W_nxt        = (const float*)d_in[14];
    const float* b_nxt        = (const float*)d_in[15];
    const float* W_self       = (const float*)d_in[16];
    const float* W_neigh      = (const float*)d_in[17];
    const float* b_sage       = (const float*)d_in[18];
    float* out = (float*)d_out;

    // Workspace layout (floats): ~123 MB total
    float* ws  = (float*)d_ws;
    float* hjA = ws;                                   // 8,000,000
    float* hjB = hjA + (size_t)N_JOB * 16;             // 8,000,000
    float* hw  = hjB + (size_t)N_JOB * 16;             // 800,000
    float* rs  = hw + (size_t)N_WORKER * 16;           // 2,500,000 (deg ints -> norm floats)
    int*   off = (int*)(rs + (size_t)5 * N_JOB);       // 1,500,000 (row offsets -> ends)
    int*   bsum = off + SCAN_N;                        // 1024
    int*   adj = bsum + 1024;                          // 10,000,000

    float* rs_in_pre  = rs + 0 * (size_t)N_JOB;
    float* rs_in_nxt  = rs + 1 * (size_t)N_JOB;
    float* inv_cnt    = rs + 2 * (size_t)N_JOB;
    float* rs_out_pre = rs + 3 * (size_t)N_JOB;
    float* rs_out_nxt = rs + 4 * (size_t)N_JOB;

    // Zero the degree region only.
    hipMemsetAsync(rs, 0, (size_t)5 * N_JOB * sizeof(float), stream);

    const int EGRID = (E_PRE + 255) / 256;

    // Windowed degree counting: atomics confined to an L2-hot node window.
    for (int w = 0; w < KWIN; ++w) {
        int wlo = w * WIN_SZ;
        int whi = (wlo + WIN_SZ < N_JOB) ? wlo + WIN_SZ : N_JOB;
        degrees_win_kernel<<<EGRID, 256, 0, stream>>>(
            pre_src, pre_dst, nxt_src, nxt_dst, proc_dst, (int*)rs, wlo, whi);
    }

    // CSR row offsets from concatenated in-degrees.
    scan_blocksum<<<SCAN_NB, 256, 0, stream>>>((const int*)rs, bsum, SCAN_N);
    scan_bsum<<<1, 1024, 0, stream>>>(bsum, SCAN_NB);
    scan_final<<<SCAN_NB, 256, 0, stream>>>((const int*)rs, bsum, off, SCAN_N);

    // Windowed placement: off-atomics + adj writes confined to L2-hot slices.
    for (int w = 0; w < KWIN; ++w) {
        int wlo = w * WIN_SZ;
        int whi = (wlo + WIN_SZ < N_JOB) ? wlo + WIN_SZ : N_JOB;
        placement_win_kernel<<<EGRID, 256, 0, stream>>>(
            pre_src, pre_dst, nxt_src, nxt_dst, proc_src, proc_dst, off, adj, wlo, whi);
    }

    convert_kernel<<<(5 * N_JOB + 255) / 256, 256, 0, stream>>>(rs);

    embed_kernel<7><<<(N_JOB + 255) / 256, 256, 0, stream>>>(job_feat, W_emb_job, b_emb_job, hjA, N_JOB);
    embed_kernel<3><<<(N_WORKER + 255) / 256, 256, 0, stream>>>(worker_feat, W_emb_worker, b_emb_worker, hw, N_WORKER);

    const int GGRID = (4 * N_JOB + 255) / 256;
    float* cur = hjA;
    float* nx  = hjB;
    for (int it = 0; it < 2; it++) {
        gather_gc_first<<<GGRID, 256, 0, stream>>>(cur, rs_out_pre, rs_in_pre, adj,
                                                   off + 0 * N_JOB, 0, W_pre,
                                                   b_pre, b_nxt, b_sage, nx);
        gather_gc_acc<<<GGRID, 256, 0, stream>>>(cur, rs_out_nxt, rs_in_nxt, adj,
                                                 off + 1 * N_JOB, E_PRE, W_nxt, nx);
        gather_sage<<<GGRID, 256, 0, stream>>>(hw, inv_cnt, adj, off + 2 * N_JOB,
                                               E_PRE + E_NXT, W_neigh, W_self, cur, nx);
        float* tmp = cur; cur = nx; nx = tmp;
    }

    scores_kernel<<<(E_PROC + 255) / 256, 256, 0, stream>>>(hw, cur, proc_src, proc_dst, out);
}

// Round 4
// 1785.924 us; speedup vs baseline: 2.7445x; 1.0217x over previous
//
#include <hip/hip_runtime.h>

#define N_JOB 500000
#define N_WORKER 50000
#define E_PRE 4000000
#define E_NXT 4000000
#define E_PROC 2000000
#define BASE_NXT E_PRE
#define BASE_PROC (E_PRE + E_NXT)
#define EHALF 2000000              // E_PRE/2 == E_NXT/2 == E_PROC

#define SCAN_N (3 * N_JOB)         // concatenated in-degrees: [in_pre | in_nxt | in_proc]
#define SCAN_BLK 2048              // 256 threads * 8 elems
#define SCAN_NB ((SCAN_N + SCAN_BLK - 1) / SCAN_BLK)   // 733 (must be <= 1024)

#define KWIN 8                     // placement windows
#define WIN_SZ ((N_JOB + KWIN - 1) / KWIN)             // 62500
#define KWIN_DEG 2                 // degree-count windows
#define WIN_DEG ((N_JOB + KWIN_DEG - 1) / KWIN_DEG)    // 250000

// ---------------------------------------------------------------------------
// Windowed degree counting, 2 edges/thread ILP. deg layout (5*N_JOB ints):
//   [0]=in_pre  [1]=in_nxt  [2]=in_proc  [3]=out_pre  [4]=out_nxt
// ---------------------------------------------------------------------------
__global__ void degrees_win2(const int* __restrict__ pre_src, const int* __restrict__ pre_dst,
                             const int* __restrict__ nxt_src, const int* __restrict__ nxt_dst,
                             const int* __restrict__ proc_dst, int* __restrict__ deg,
                             int wlo, int whi) {
    int i = blockIdx.x * blockDim.x + threadIdx.x;
    if (i >= EHALF) return;
#pragma unroll
    for (int j = 0; j < 2; ++j) {
        int k = i + j * EHALF;
        int d0 = pre_dst[k], s0 = pre_src[k];
        int d1 = nxt_dst[k], s1 = nxt_src[k];
        if (d0 >= wlo && d0 < whi) atomicAdd(&deg[0 * N_JOB + d0], 1);
        if (s0 >= wlo && s0 < whi) atomicAdd(&deg[3 * N_JOB + s0], 1);
        if (d1 >= wlo && d1 < whi) atomicAdd(&deg[1 * N_JOB + d1], 1);
        if (s1 >= wlo && s1 < whi) atomicAdd(&deg[4 * N_JOB + s1], 1);
    }
    int dp = proc_dst[i];
    if (dp >= wlo && dp < whi) atomicAdd(&deg[2 * N_JOB + dp], 1);
}

// Convert out-degree ints (segments 3,4) -> rsqrt floats in place.
__global__ void convert_out(float* __restrict__ base) {
    int i = blockIdx.x * blockDim.x + threadIdx.x;
    if (i >= 2 * N_JOB) return;
    int d = ((const int*)base)[i];
    base[i] = rsqrtf((float)(d < 1 ? 1 : d));
}

// ---------------------------------------------------------------------------
// Exclusive scan over SCAN_N ints (3-kernel two-level scan).
// ---------------------------------------------------------------------------
__global__ void scan_blocksum(const int* __restrict__ in, int* __restrict__ bsum, int n) {
    __shared__ int sd[256];
    int t = threadIdx.x;
    int base = blockIdx.x * SCAN_BLK + t * 8;
    int sum = 0;
#pragma unroll
    for (int j = 0; j < 8; ++j) {
        int idx = base + j;
        if (idx < n) sum += in[idx];
    }
    sd[t] = sum;
    __syncthreads();
    for (int o = 128; o > 0; o >>= 1) {
        if (t < o) sd[t] += sd[t + o];
        __syncthreads();
    }
    if (t == 0) bsum[blockIdx.x] = sd[0];
}

__global__ void scan_bsum(int* __restrict__ bsum, int nb) {
    __shared__ int s[1024];
    int t = threadIdx.x;
    int orig = (t < nb) ? bsum[t] : 0;
    s[t] = orig;
    __syncthreads();
    for (int o = 1; o < 1024; o <<= 1) {
        int v = (t >= o) ? s[t - o] : 0;
        __syncthreads();
        s[t] += v;
        __syncthreads();
    }
    if (t < nb) bsum[t] = s[t] - orig;  // exclusive
}

__global__ void scan_final(const int* __restrict__ in, const int* __restrict__ bsum,
                           int* __restrict__ off, int n) {
    __shared__ int sd[256];
    int t = threadIdx.x;
    int base = blockIdx.x * SCAN_BLK + t * 8;
    int vals[8];
    int tsum = 0;
#pragma unroll
    for (int j = 0; j < 8; ++j) {
        int idx = base + j;
        vals[j] = (idx < n) ? in[idx] : 0;
        tsum += vals[j];
    }
    sd[t] = tsum;
    __syncthreads();
    for (int o = 1; o < 256; o <<= 1) {
        int v = (t >= o) ? sd[t - o] : 0;
        __syncthreads();
        sd[t] += v;
        __syncthreads();
    }
    int run = bsum[blockIdx.x] + sd[t] - tsum;  // block base + exclusive thread prefix
#pragma unroll
    for (int j = 0; j < 8; ++j) {
        int idx = base + j;
        if (idx < n) off[idx] = run;
        run += vals[j];
    }
}

// ---------------------------------------------------------------------------
// Windowed CSR placement, ILP: 2 pre + 2 nxt + 1 proc edge per thread.
// off holds global edge ids: pre [0,4M), nxt [4M,8M), proc [8M,10M).
// adj_jj gets src for pre/nxt; adj_proc gets (src, edge_id) for proc.
// ---------------------------------------------------------------------------
__global__ void placement_win2(const int* __restrict__ pre_src, const int* __restrict__ pre_dst,
                               const int* __restrict__ nxt_src, const int* __restrict__ nxt_dst,
                               const int* __restrict__ proc_src, const int* __restrict__ proc_dst,
                               int* __restrict__ off, int* __restrict__ adj_jj,
                               int2* __restrict__ adj_proc, int wlo, int whi) {
    int i = blockIdx.x * blockDim.x + threadIdx.x;
    if (i >= EHALF) return;
#pragma unroll
    for (int j = 0; j < 2; ++j) {
        int k = i + j * EHALF;
        int d0 = pre_dst[k];
        if (d0 >= wlo && d0 < whi) {
            int p = atomicAdd(&off[0 * N_JOB + d0], 1);
            adj_jj[p] = pre_src[k];
        }
        int d1 = nxt_dst[k];
        if (d1 >= wlo && d1 < whi) {
            int p = atomicAdd(&off[1 * N_JOB + d1], 1);
            adj_jj[p] = nxt_src[k];
        }
    }
    int dp = proc_dst[i];
    if (dp >= wlo && dp < whi) {
        int p = atomicAdd(&off[2 * N_JOB + dp], 1);
        adj_proc[p - BASE_PROC] = make_int2(proc_src[i], i);
    }
}

// ---------------------------------------------------------------------------
// Embedding: one thread per row, weights staged in LDS.
// ---------------------------------------------------------------------------
template <int F>
__global__ void embed_kernel(const float* __restrict__ feat, const float* __restrict__ W,
                             const float* __restrict__ b, float* __restrict__ out, int n) {
    __shared__ float Ws[F * 16];
    __shared__ float bs[16];
    int t = threadIdx.x;
    if (t < F * 16) Ws[t] = W[t];
    if (t < 16) bs[t] = b[t];
    __syncthreads();
    int i = blockIdx.x * blockDim.x + t;
    if (i >= n) return;
    float f[F];
#pragma unroll
    for (int k = 0; k < F; k++) f[k] = feat[(size_t)i * F + k];
    float o[16];
#pragma unroll
    for (int d = 0; d < 16; d++) {
        float s = bs[d];
#pragma unroll
        for (int k = 0; k < F; k++) s += f[k] * Ws[k * 16 + d];
        o[d] = s;
    }
    float4* dst4 = (float4*)(out + (size_t)i * 16);
    dst4[0] = make_float4(o[0], o[1], o[2], o[3]);
    dst4[1] = make_float4(o[4], o[5], o[6], o[7]);
    dst4[2] = make_float4(o[8], o[9], o[10], o[11]);
    dst4[3] = make_float4(o[12], o[13], o[14], o[15]);
}

// ---------------------------------------------------------------------------
// Merged per-layer gather: pre-conv + nxt-conv + sage(mean) + self, one kernel.
// 4 lanes per node; lane c owns float4 chunk c. In-degree normalizers come
// from row lengths. FINAL also computes the dot-product readout using the
// just-computed hj chunk against L2-warm hw rows (adj_proc carries edge ids).
// ---------------------------------------------------------------------------
__device__ __forceinline__ void mm_accum(const float* __restrict__ Ws, float4 a, int c, float o[4]) {
#pragma unroll
    for (int g = 0; g < 4; ++g) {
        float a0 = __shfl(a.x, g, 4);
        float a1 = __shfl(a.y, g, 4);
        float a2 = __shfl(a.z, g, 4);
        float a3 = __shfl(a.w, g, 4);
        const float* wr = &Ws[(4 * g) * 16 + c * 4];
#pragma unroll
        for (int j = 0; j < 4; ++j)
            o[j] += a0 * wr[j] + a1 * wr[16 + j] + a2 * wr[32 + j] + a3 * wr[48 + j];
    }
}

template <bool FINAL>
__global__ void gather_layer(const float* __restrict__ cur, const float* __restrict__ hwk,
                             const int* __restrict__ adj_jj, const int2* __restrict__ adj_proc,
                             const int* __restrict__ off,
                             const float* __restrict__ sc_pre, const float* __restrict__ sc_nxt,
                             const float* __restrict__ Wp, const float* __restrict__ Wn,
                             const float* __restrict__ Wng, const float* __restrict__ Wsf,
                             const float* __restrict__ bp, const float* __restrict__ bn,
                             const float* __restrict__ bsg,
                             float* __restrict__ out, float* __restrict__ scores) {
    __shared__ float WpS[256], WnS[256], WngS[256], WsfS[256], bs[16];
    int t = threadIdx.x;
    WpS[t] = Wp[t]; WnS[t] = Wn[t]; WngS[t] = Wng[t]; WsfS[t] = Wsf[t];
    if (t < 16) bs[t] = bp[t] + bn[t] + bsg[t];
    __syncthreads();
    unsigned gid = blockIdx.x * 256 + t;
    unsigned v = gid >> 2, c = gid & 3;
    if (v >= N_JOB) return;
    const int* rend0 = off;
    const int* rend1 = off + N_JOB;
    const int* rend2 = off + 2 * N_JOB;
    int e0 = rend0[v], s0 = v ? rend0[v - 1] : 0;
    int e1 = rend1[v], s1 = v ? rend1[v - 1] : BASE_NXT;
    int e2 = rend2[v] - BASE_PROC;
    int s2 = (v ? rend2[v - 1] : BASE_PROC) - BASE_PROC;

    // precede-conv aggregation (scaled by rsqrt(out_deg) of src)
    float4 accP = make_float4(0.f, 0.f, 0.f, 0.f);
    {
        int p = s0;
        for (; p + 1 < e0; p += 2) {
            int sa = adj_jj[p], sb = adj_jj[p + 1];
            float wa = sc_pre[sa], wb = sc_pre[sb];
            float4 ha = ((const float4*)(cur + (size_t)sa * 16))[c];
            float4 hb = ((const float4*)(cur + (size_t)sb * 16))[c];
            accP.x += ha.x * wa + hb.x * wb; accP.y += ha.y * wa + hb.y * wb;
            accP.z += ha.z * wa + hb.z * wb; accP.w += ha.w * wa + hb.w * wb;
        }
        if (p < e0) {
            int sa = adj_jj[p];
            float wa = sc_pre[sa];
            float4 ha = ((const float4*)(cur + (size_t)sa * 16))[c];
            accP.x += ha.x * wa; accP.y += ha.y * wa; accP.z += ha.z * wa; accP.w += ha.w * wa;
        }
    }
    // next-conv aggregation
    float4 accN = make_float4(0.f, 0.f, 0.f, 0.f);
    {
        int p = s1;
        for (; p + 1 < e1; p += 2) {
            int sa = adj_jj[p], sb = adj_jj[p + 1];
            float wa = sc_nxt[sa], wb = sc_nxt[sb];
            float4 ha = ((const float4*)(cur + (size_t)sa * 16))[c];
            float4 hb = ((const float4*)(cur + (size_t)sb * 16))[c];
            accN.x += ha.x * wa + hb.x * wb; accN.y += ha.y * wa + hb.y * wb;
            accN.z += ha.z * wa + hb.z * wb; accN.w += ha.w * wa + hb.w * wb;
        }
        if (p < e1) {
            int sa = adj_jj[p];
            float wa = sc_nxt[sa];
            float4 ha = ((const float4*)(cur + (size_t)sa * 16))[c];
            accN.x += ha.x * wa; accN.y += ha.y * wa; accN.z += ha.z * wa; accN.w += ha.w * wa;
        }
    }
    // sage mean aggregation over worker neighbors
    float4 accS = make_float4(0.f, 0.f, 0.f, 0.f);
    {
        int p = s2;
        for (; p + 1 < e2; p += 2) {
            int2 pa = adj_proc[p], pb = adj_proc[p + 1];
            float4 ha = ((const float4*)(hwk + (size_t)pa.x * 16))[c];
            float4 hb = ((const float4*)(hwk + (size_t)pb.x * 16))[c];
            accS.x += ha.x + hb.x; accS.y += ha.y + hb.y;
            accS.z += ha.z + hb.z; accS.w += ha.w + hb.w;
        }
        if (p < e2) {
            int2 pa = adj_proc[p];
            float4 ha = ((const float4*)(hwk + (size_t)pa.x * 16))[c];
            accS.x += ha.x; accS.y += ha.y; accS.z += ha.z; accS.w += ha.w;
        }
    }

    int d0 = e0 - s0, d1 = e1 - s1, d2 = e2 - s2;
    float rp = rsqrtf((float)(d0 < 1 ? 1 : d0));
    float rn = rsqrtf((float)(d1 < 1 ? 1 : d1));
    float ri = 1.0f / (float)(d2 < 1 ? 1 : d2);
    accP.x *= rp; accP.y *= rp; accP.z *= rp; accP.w *= rp;
    accN.x *= rn; accN.y *= rn; accN.z *= rn; accN.w *= rn;
    accS.x *= ri; accS.y *= ri; accS.z *= ri; accS.w *= ri;

    float o[4];
#pragma unroll
    for (int j = 0; j < 4; ++j) o[j] = bs[c * 4 + j];
    mm_accum(WpS, accP, c, o);
    mm_accum(WnS, accN, c, o);
    mm_accum(WngS, accS, c, o);
    float4 hself = ((const float4*)(cur + (size_t)v * 16))[c];
    mm_accum(WsfS, hself, c, o);
    ((float4*)(out + (size_t)v * 16))[c] = make_float4(o[0], o[1], o[2], o[3]);

    if (FINAL) {
        // readout: dot(hw[u], hj_new[v]) per proc edge, hw rows are L2-warm
        for (int p = s2; p < e2; ++p) {
            int2 pr = adj_proc[p];
            float4 wv = ((const float4*)(hwk + (size_t)pr.x * 16))[c];
            float d = o[0] * wv.x + o[1] * wv.y + o[2] * wv.z + o[3] * wv.w;
            d += __shfl_xor(d, 1, 4);
            d += __shfl_xor(d, 2, 4);
            if (c == 0) scores[pr.y] = d;
        }
    }
}

extern "C" void kernel_launch(void* const* d_in, const int* in_sizes, int n_in,
                              void* d_out, int out_size, void* d_ws, size_t ws_size,
                              hipStream_t stream) {
    const float* job_feat     = (const float*)d_in[0];
    const float* worker_feat  = (const float*)d_in[1];
    const int*   pre_src      = (const int*)d_in[2];
    const int*   pre_dst      = (const int*)d_in[3];
    const int*   nxt_src      = (const int*)d_in[4];
    const int*   nxt_dst      = (const int*)d_in[5];
    const int*   proc_src     = (const int*)d_in[6];
    const int*   proc_dst     = (const int*)d_in[7];
    const float* W_emb_job    = (const float*)d_in[8];
    const float* b_emb_job    = (const float*)d_in[9];
    const float* W_emb_worker = (const float*)d_in[10];
    const float* b_emb_worker = (const float*)d_in[11];
    const float* W_pre        = (const float*)d_in[12];
    const float* b_pre        = (const float*)d_in[13];
    const float* W_nxt        = (const float*)d_in[14];
    const float* b_nxt        = (const float*)d_in[15];
    const float* W_self       = (const float*)d_in[16];
    const float* W_neigh      = (const float*)d_in[17];
    const float* b_sage       = (const float*)d_in[18];
    float* out = (float*)d_out;

    // Workspace layout (ints/floats), ~131 MB total
    float* ws   = (float*)d_ws;
    float* hjA  = ws;                                   // 8,000,000 f
    float* hjB  = hjA + (size_t)N_JOB * 16;             // 8,000,000 f
    float* hw   = hjB + (size_t)N_JOB * 16;             //   800,000 f
    float* rs   = hw + (size_t)N_WORKER * 16;           // 2,500,000 (deg ints -> norm floats)
    int*   off  = (int*)(rs + (size_t)5 * N_JOB);       // 1,500,000 (row offsets -> ends)
    int*   bsum = off + SCAN_N;                         // 1024
    int*   adj_jj = bsum + 1024;                        // 8,000,000
    int2*  adj_proc = (int2*)(adj_jj + (size_t)(E_PRE + E_NXT)); // 2,000,000 int2

    float* sc_pre = rs + 3 * (size_t)N_JOB;             // rsqrt(out_deg) pre
    float* sc_nxt = rs + 4 * (size_t)N_JOB;             // rsqrt(out_deg) nxt

    hipMemsetAsync(rs, 0, (size_t)5 * N_JOB * sizeof(float), stream);

    const int HGRID = (EHALF + 255) / 256;

    // Degree counting: 2 windows, 2-edge-per-thread ILP.
    for (int w = 0; w < KWIN_DEG; ++w) {
        int wlo = w * WIN_DEG;
        int whi = (wlo + WIN_DEG < N_JOB) ? wlo + WIN_DEG : N_JOB;
        degrees_win2<<<HGRID, 256, 0, stream>>>(
            pre_src, pre_dst, nxt_src, nxt_dst, proc_dst, (int*)rs, wlo, whi);
    }

    // CSR row offsets from concatenated in-degrees.
    scan_blocksum<<<SCAN_NB, 256, 0, stream>>>((const int*)rs, bsum, SCAN_N);
    scan_bsum<<<1, 1024, 0, stream>>>(bsum, SCAN_NB);
    scan_final<<<SCAN_NB, 256, 0, stream>>>((const int*)rs, bsum, off, SCAN_N);

    // Out-degree normalizers (segments 3,4 only; in-degs come from row lengths).
    convert_out<<<(2 * N_JOB + 255) / 256, 256, 0, stream>>>(rs + 3 * (size_t)N_JOB);

    // Windowed placement with ILP.
    for (int w = 0; w < KWIN; ++w) {
        int wlo = w * WIN_SZ;
        int whi = (wlo + WIN_SZ < N_JOB) ? wlo + WIN_SZ : N_JOB;
        placement_win2<<<HGRID, 256, 0, stream>>>(
            pre_src, pre_dst, nxt_src, nxt_dst, proc_src, proc_dst,
            off, adj_jj, adj_proc, wlo, whi);
    }

    embed_kernel<7><<<(N_JOB + 255) / 256, 256, 0, stream>>>(job_feat, W_emb_job, b_emb_job, hjA, N_JOB);
    embed_kernel<3><<<(N_WORKER + 255) / 256, 256, 0, stream>>>(worker_feat, W_emb_worker, b_emb_worker, hw, N_WORKER);

    const int GGRID = (4 * N_JOB + 255) / 256;
    gather_layer<false><<<GGRID, 256, 0, stream>>>(
        hjA, hw, adj_jj, adj_proc, off, sc_pre, sc_nxt,
        W_pre, W_nxt, W_neigh, W_self, b_pre, b_nxt, b_sage, hjB, nullptr);
    gather_layer<true><<<GGRID, 256, 0, stream>>>(
        hjB, hw, adj_jj, adj_proc, off, sc_pre, sc_nxt,
        W_pre, W_nxt, W_neigh, W_self, b_pre, b_nxt, b_sage, hjA, out);
}